// Round 6
// baseline (734.326 us; speedup 1.0000x reference)
//
#include <hip/hip_runtime.h>

typedef _Float16 half_t;
typedef _Float16 half8  __attribute__((ext_vector_type(8)));
typedef _Float16 half4v __attribute__((ext_vector_type(4)));
typedef float    f32x4  __attribute__((ext_vector_type(4)));

#define AS1 __attribute__((address_space(1)))
#define AS3 __attribute__((address_space(3)))

#define MODE_H16  0   // store fp16
#define MODE_F32R 1   // store fp32 = acc + bias + residual
#define MODE_GELU 2   // store fp16 = gelu(acc + bias)

__device__ __forceinline__ f32x4 zero4() {
    f32x4 z; z[0] = 0.f; z[1] = 0.f; z[2] = 0.f; z[3] = 0.f; return z;
}

__device__ __forceinline__ half8 lds_frag(const half_t* p) {
    union { uint4 u; half8 h; } c;
    c.u = *(const uint4*)p;
    return c.h;
}

// fast tanh-GELU: v*sigmoid(1.59577(v+0.044715 v^3)); |err| ~3e-4
__device__ __forceinline__ float gelu_f(float v) {
    float t = v * v;
    float u = v * (1.595769122f + 0.0713548163f * t);
    return v / (1.f + __expf(-u));
}

__device__ __forceinline__ float fexp2(float x) {
    return __builtin_amdgcn_exp2f(x);
}

// async global->LDS, 16B/lane; LDS dest is wave-uniform base + lane*16
__device__ __forceinline__ void gl_lds16(const half_t* g, half_t* l) {
    __builtin_amdgcn_global_load_lds(
        (AS1 unsigned int*)(unsigned long long)(const void*)g,
        (AS3 unsigned int*)l,
        16, 0, 0);
}

// ---------------------------------------------------------------------------
// Swizzle convention (shared by all tiles): logical 8-half chunk c of row r
// lives at phys chunk c^(r&7).  Staging lane at phys chunk p of row r reads
// source chunk p^(r&7); reader of logical chunk c applies the same XOR.
// ---------------------------------------------------------------------------

// ===========================================================================
// 256x256 GEMM core, counted-vmcnt 3-phase schedule (T3+T4).
// BM=BN=256, BK=64, 512 thr = 8 waves (2M x 4N), per-wave out 128x64.
// LDS 128 KiB: A/B each 2 bufs x [256][64] half.
//
// Per-iter phases (buf d = t&1, prefetch -> buf d^1):
//  P1: read ALL bf (B-cur) | stage B(t+1) (4 gl_lds) | vmcnt(4)* | bar
//      (*ensures A-cur, the 4 oldest outstanding; B(t+1) stays in flight)
//  P2: read af half0       | stage A(t+1) (4)        | bar | 32 MFMA | bar
//  P3: read af half1       |                           bar | 32 MFMA |
//      vmcnt(4)* | bar    (*ensures B(t+1); A(t+1) stays in flight)
// vmcnt NEVER drains to 0 in steady state (m218 lever); last iter peels
// to vmcnt(0) since no new loads cover the counted wait.
// Cross-wave safety: every wave issues the identical load sequence, so
// "own loads ensured + barrier" => "all waves' loads ensured".
// ===========================================================================

__device__ __forceinline__ void stage_half(
    const half_t* __restrict__ G, half_t* L, int K, int srow, int sck, int w)
{
    // 16 KB half-tile = 128 rows x 64 halfs; 2 gl_lds per thread.
    gl_lds16(G + (size_t)srow * K + sck,        L + w * 512);
    gl_lds16(G + (size_t)(64 + srow) * K + sck, L + 4096 + w * 512);
}

#define LDA(MH)                                                              \
    _Pragma("unroll")                                                        \
    for (int m = 0; m < 4; m++) {                                            \
        af[m][0] = lds_frag(&Ad[abase + (MH) * 4096 + m * 1024 + c0]);       \
        af[m][1] = lds_frag(&Ad[abase + (MH) * 4096 + m * 1024 + c1]);       \
    }

#define LDB(NH)                                                              \
    _Pragma("unroll")                                                        \
    for (int n = 0; n < 2; n++) {                                            \
        bf[NH][n][0] = lds_frag(&Bd[bbase + (NH) * 2048 + n * 1024 + c0]);   \
        bf[NH][n][1] = lds_frag(&Bd[bbase + (NH) * 2048 + n * 1024 + c1]);   \
    }

#define MFMA_Q(MH, NH)                                                       \
    _Pragma("unroll")                                                        \
    for (int m = 0; m < 4; m++)                                              \
        _Pragma("unroll")                                                    \
        for (int n = 0; n < 2; n++) {                                        \
            acc[(MH)*4 + m][(NH)*2 + n] =                                    \
                __builtin_amdgcn_mfma_f32_16x16x32_f16(                      \
                    af[m][0], bf[NH][n][0], acc[(MH)*4 + m][(NH)*2 + n],     \
                    0, 0, 0);                                                \
            acc[(MH)*4 + m][(NH)*2 + n] =                                    \
                __builtin_amdgcn_mfma_f32_16x16x32_f16(                      \
                    af[m][1], bf[NH][n][1], acc[(MH)*4 + m][(NH)*2 + n],     \
                    0, 0, 0);                                                \
        }

__device__ __forceinline__ void mfma_core256(
    const half_t* __restrict__ Ag, const half_t* __restrict__ Bg, int K,
    half_t* As, half_t* Bs, f32x4 (&acc)[8][4])
{
    const int tid  = threadIdx.x;
    const int w    = tid >> 6, lane = tid & 63;
    const int wm   = w >> 2, wn = w & 3;
    const int g    = lane >> 4, ml = lane & 15, m7 = ml & 7;
    const int srow = tid >> 3;
    const int sck  = ((tid & 7) ^ (srow & 7)) * 8;

#pragma unroll
    for (int i = 0; i < 8; i++)
#pragma unroll
        for (int j = 0; j < 4; j++) acc[i][j] = zero4();

    const int abase = (wm * 128 + ml) * 64;       // wave's A row base in LDS
    const int bbase = (wn * 64 + ml) * 64;        // wave's B row base in LDS
    const int c0 = (g ^ m7) * 8, c1 = ((4 + g) ^ m7) * 8;   // kk=0/1 chunks

    // prologue: tile 0 -> buf 0 (8 gl_lds), full drain once.
    stage_half(Bg, Bs, K, srow, sck, w);
    stage_half(Bg + (size_t)128 * K, Bs + 8192, K, srow, sck, w);
    stage_half(Ag, As, K, srow, sck, w);
    stage_half(Ag + (size_t)128 * K, As + 8192, K, srow, sck, w);
    asm volatile("s_waitcnt vmcnt(0)" ::: "memory");
    __builtin_amdgcn_s_barrier();

    const int NT = K >> 6;
    half8 af[4][2];
    half8 bf[2][2][2];

    for (int t = 0; t < NT; ++t) {
        half_t* Ad = As + (t & 1) * 16384;
        half_t* Bd = Bs + (t & 1) * 16384;
        half_t* An = As + ((t + 1) & 1) * 16384;
        half_t* Bn = Bs + ((t + 1) & 1) * 16384;
        const half_t* Agn = Ag + (t + 1) * 64;
        const half_t* Bgn = Bg + (t + 1) * 64;
        const bool pf = (t + 1 < NT);

        // ---- P1: all B-cur fragments; stage B(t+1); ensure A-cur.
        LDB(0)
        LDB(1)
        if (pf) {
            stage_half(Bgn, Bn, K, srow, sck, w);
            stage_half(Bgn + (size_t)128 * K, Bn + 8192, K, srow, sck, w);
            asm volatile("s_waitcnt vmcnt(4)" ::: "memory");
        } else {
            asm volatile("s_waitcnt vmcnt(0)" ::: "memory");
        }
        __builtin_amdgcn_s_barrier();

        // ---- P2: A half0; stage A(t+1); MFMA quadrants (0,0)+(0,1).
        LDA(0)
        if (pf) {
            stage_half(Agn, An, K, srow, sck, w);
            stage_half(Agn + (size_t)128 * K, An + 8192, K, srow, sck, w);
        }
        __builtin_amdgcn_s_barrier();
        __builtin_amdgcn_s_setprio(1);
        MFMA_Q(0, 0)
        MFMA_Q(0, 1)
        __builtin_amdgcn_s_setprio(0);
        __builtin_amdgcn_s_barrier();

        // ---- P3: A half1; MFMA quadrants (1,0)+(1,1); ensure B(t+1).
        LDA(1)
        __builtin_amdgcn_s_barrier();
        __builtin_amdgcn_s_setprio(1);
        MFMA_Q(1, 0)
        MFMA_Q(1, 1)
        __builtin_amdgcn_s_setprio(0);
        if (pf) {
            asm volatile("s_waitcnt vmcnt(4)" ::: "memory");
        } else {
            asm volatile("s_waitcnt vmcnt(0)" ::: "memory");
        }
        __builtin_amdgcn_s_barrier();
    }
}

// ---------------------------------------------------------------------------
// C[M,N] = A[M,K] @ Bt[N,K]^T + bias, fused epilogues. 256x256 tile.
// ---------------------------------------------------------------------------
__global__ __launch_bounds__(512, 2) void gemm256_bt(
    const half_t* __restrict__ A,
    const half_t* __restrict__ Bt,
    const float*  __restrict__ bias,
    const float*  __restrict__ res,
    void* __restrict__ out,
    int M, int N, int K, int mode)
{
    __shared__ __align__(16) half_t As[2 * 16384];
    __shared__ __align__(16) half_t Bs[2 * 16384];

    const int m0 = blockIdx.y * 256, n0 = blockIdx.x * 256;
    f32x4 acc[8][4];
    mfma_core256(A + (size_t)m0 * K, Bt + (size_t)n0 * K, K, As, Bs, acc);

    const int tid = threadIdx.x;
    const int w   = tid >> 6, lane = tid & 63;
    const int wm  = w >> 2, wn = w & 3;
    const int g   = lane >> 4, ml = lane & 15;
    const int gm0 = m0 + wm * 128, gn0 = n0 + wn * 64;

#pragma unroll
    for (int nj = 0; nj < 4; nj++) {
        int col = gn0 + nj * 16 + ml;
        float bv = bias[col];
#pragma unroll
        for (int mi = 0; mi < 8; mi++) {
#pragma unroll
            for (int r = 0; r < 4; r++) {
                int row = gm0 + mi * 16 + g * 4 + r;
                float v = acc[mi][nj][r] + bv;
                size_t idx = (size_t)row * N + col;
                if (mode == MODE_F32R) {
                    ((float*)out)[idx] = v + res[idx];
                } else if (mode == MODE_GELU) {
                    ((half_t*)out)[idx] = (half_t)gelu_f(v);
                } else {
                    ((half_t*)out)[idx] = (half_t)v;
                }
            }
        }
    }
}

// ---------------------------------------------------------------------------
// Fused QKV GEMM, 256x256 tile: N=3072 (Wq|Wk|Wv transposed, contiguous).
// ---------------------------------------------------------------------------
__global__ __launch_bounds__(512, 2) void gemm256_qkv(
    const half_t* __restrict__ A,
    const half_t* __restrict__ Bt,
    const float*  __restrict__ bq,
    const float*  __restrict__ bk,
    const float*  __restrict__ bv,
    half_t* __restrict__ Qo, half_t* __restrict__ Ko, half_t* __restrict__ Vto,
    int M, int K)
{
    __shared__ __align__(16) half_t As[2 * 16384];
    __shared__ __align__(16) half_t Bs[2 * 16384];

    const int m0 = blockIdx.y * 256, n0 = blockIdx.x * 256;
    f32x4 acc[8][4];
    mfma_core256(A + (size_t)m0 * K, Bt + (size_t)n0 * K, K, As, Bs, acc);

    const int tid = threadIdx.x;
    const int w   = tid >> 6, lane = tid & 63;
    const int wm  = w >> 2, wn = w & 3;
    const int g   = lane >> 4, ml = lane & 15;

    const int seg   = n0 >> 10;                 // block-uniform: 0=Q,1=K,2=V
    const int nbase = (n0 & 1023) + wn * 64;
    const float* bias = (seg == 0) ? bq : (seg == 1) ? bk : bv;
    const int gm0 = m0 + wm * 128;

    if (seg < 2) {
        half_t* O = (seg == 0) ? Qo : Ko;
#pragma unroll
        for (int nj = 0; nj < 4; nj++) {
            int col = nbase + nj * 16 + ml;
            float bvv = bias[col];
#pragma unroll
            for (int mi = 0; mi < 8; mi++)
#pragma unroll
                for (int r = 0; r < 4; r++)
                    O[(size_t)(gm0 + mi * 16 + g * 4 + r) * 1024 + col] =
                        (half_t)(acc[mi][nj][r] + bvv);
        }
    } else {
#pragma unroll
        for (int nj = 0; nj < 4; nj++) {
            int col = nbase + nj * 16 + ml;
            float bvv = bias[col];
#pragma unroll
            for (int mi = 0; mi < 8; mi++) {
                int rowb = gm0 + mi * 16 + g * 4;
                int bb = rowb >> 11, sl = rowb & 2047;       // S=2048
                half4v v4;
#pragma unroll
                for (int r = 0; r < 4; r++) v4[r] = (half_t)(acc[mi][nj][r] + bvv);
                *(half4v*)&Vto[((size_t)bb * 1024 + col) * 2048 + sl] = v4;
            }
        }
    }
}

// ---------------------------------------------------------------------------
// 128x64-tile GEMM for N=1024 cases. BK=64. MODE_F32R only. (attn-out proj)
// ---------------------------------------------------------------------------
__global__ __launch_bounds__(256) void gemm_bt64(
    const half_t* __restrict__ A,
    const half_t* __restrict__ Bt,
    const float*  __restrict__ bias,
    const float*  __restrict__ res,
    float* __restrict__ out,
    int M, int N, int K)
{
    __shared__ __align__(16) half_t As[128 * 64];
    __shared__ __align__(16) half_t Bs[64 * 64];

    const int tid  = threadIdx.x;
    const int w    = tid >> 6, lane = tid & 63;
    const int m0   = blockIdx.y * 128, n0 = blockIdx.x * 64;
    const int g    = lane >> 4, ml = lane & 15, m7 = ml & 7;
    const int mo   = w * 32;
    const int r8   = lane >> 3;
    const int sck  = ((lane & 7) ^ (r8 & 7)) * 8;

    f32x4 acc[2][4];
#pragma unroll
    for (int i = 0; i < 2; i++)
#pragma unroll
        for (int j = 0; j < 4; j++) acc[i][j] = zero4();

    const half_t* Ag = A  + (size_t)m0 * K;
    const half_t* Bg = Bt + (size_t)n0 * K;

    for (int k0 = 0; k0 < K; k0 += 64) {
        __syncthreads();
#pragma unroll
        for (int i = 0; i < 4; i++) {
            int t = w * 4 + i;
            gl_lds16(Ag + (size_t)(t * 8 + r8) * K + k0 + sck, &As[t * 512]);
        }
#pragma unroll
        for (int i = 0; i < 2; i++) {
            int t = w * 2 + i;
            gl_lds16(Bg + (size_t)(t * 8 + r8) * K + k0 + sck, &Bs[t * 512]);
        }
        __syncthreads();
#pragma unroll
        for (int kk = 0; kk < 2; kk++) {
            const int co = ((kk * 4 + g) ^ m7) * 8;
            half8 af[2], bf[4];
#pragma unroll
            for (int i = 0; i < 2; i++) af[i] = lds_frag(&As[(mo + i * 16 + ml) * 64 + co]);
#pragma unroll
            for (int j = 0; j < 4; j++) bf[j] = lds_frag(&Bs[(j * 16 + ml) * 64 + co]);
#pragma unroll
            for (int i = 0; i < 2; i++)
#pragma unroll
                for (int j = 0; j < 4; j++)
                    acc[i][j] = __builtin_amdgcn_mfma_f32_16x16x32_f16(af[i], bf[j], acc[i][j], 0, 0, 0);
        }
    }

    const int gm0 = m0 + mo;
#pragma unroll
    for (int j = 0; j < 4; j++) {
        int col = n0 + j * 16 + ml;
        float bv = bias[col];
#pragma unroll
        for (int i = 0; i < 2; i++) {
#pragma unroll
            for (int r = 0; r < 4; r++) {
                int row = gm0 + i * 16 + g * 4 + r;
                size_t idx = (size_t)row * N + col;
                out[idx] = acc[i][j][r] + bv + res[idx];
            }
        }
    }
}

// ---------------------------------------------------------------------------
// Split-K=2 partial 128x64-tile GEMM: part[z][M][N] = A[M,zslice]@Bt[N,zslice]^T
// (no bias/res; reduce fused into layernorm_sk2).  grid.z = 2, KS = K/2.
// ---------------------------------------------------------------------------
__global__ __launch_bounds__(256) void gemm_bt64_sk(
    const half_t* __restrict__ A,
    const half_t* __restrict__ Bt,
    float* __restrict__ part,
    int M, int N, int K, int KS)
{
    __shared__ __align__(16) half_t As[128 * 64];
    __shared__ __align__(16) half_t Bs[64 * 64];

    const int tid  = threadIdx.x;
    const int w    = tid >> 6, lane = tid & 63;
    const int m0   = blockIdx.y * 128, n0 = blockIdx.x * 64;
    const int sk   = blockIdx.z;
    const int g    = lane >> 4, ml = lane & 15, m7 = ml & 7;
    const int mo   = w * 32;
    const int r8   = lane >> 3;
    const int sck  = ((lane & 7) ^ (r8 & 7)) * 8;

    f32x4 acc[2][4];
#pragma unroll
    for (int i = 0; i < 2; i++)
#pragma unroll
        for (int j = 0; j < 4; j++) acc[i][j] = zero4();

    const half_t* Ag = A  + (size_t)m0 * K + (size_t)sk * KS;
    const half_t* Bg = Bt + (size_t)n0 * K + (size_t)sk * KS;

    for (int k0 = 0; k0 < KS; k0 += 64) {
        __syncthreads();
#pragma unroll
        for (int i = 0; i < 4; i++) {
            int t = w * 4 + i;
            gl_lds16(Ag + (size_t)(t * 8 + r8) * K + k0 + sck, &As[t * 512]);
        }
#pragma unroll
        for (int i = 0; i < 2; i++) {
            int t = w * 2 + i;
            gl_lds16(Bg + (size_t)(t * 8 + r8) * K + k0 + sck, &Bs[t * 512]);
        }
        __syncthreads();
#pragma unroll
        for (int kk = 0; kk < 2; kk++) {
            const int co = ((kk * 4 + g) ^ m7) * 8;
            half8 af[2], bf[4];
#pragma unroll
            for (int i = 0; i < 2; i++) af[i] = lds_frag(&As[(mo + i * 16 + ml) * 64 + co]);
#pragma unroll
            for (int j = 0; j < 4; j++) bf[j] = lds_frag(&Bs[(j * 16 + ml) * 64 + co]);
#pragma unroll
            for (int i = 0; i < 2; i++)
#pragma unroll
                for (int j = 0; j < 4; j++)
                    acc[i][j] = __builtin_amdgcn_mfma_f32_16x16x32_f16(af[i], bf[j], acc[i][j], 0, 0, 0);
        }
    }

    const int gm0 = m0 + mo;
    float* P = part + (size_t)sk * M * N;
#pragma unroll
    for (int j = 0; j < 4; j++) {
        int col = n0 + j * 16 + ml;
#pragma unroll
        for (int i = 0; i < 2; i++) {
#pragma unroll
            for (int r = 0; r < 4; r++) {
                int row = gm0 + i * 16 + g * 4 + r;
                P[(size_t)row * N + col] = acc[i][j][r];
            }
        }
    }
}

// ---------------------------------------------------------------------------
// Flash attention v4b: kv-split x2, single-buffer gl_lds staging, log2
// softmax + defer-max.  (Structure proven rounds 1/5.)
// ---------------------------------------------------------------------------
__global__ __launch_bounds__(256, 4) void flash_attn(
    const half_t* __restrict__ Q,
    const half_t* __restrict__ Kq,
    const half_t* __restrict__ Vt,
    const float*  __restrict__ mask,   // [B*S] additive (nat-log domain)
    half_t* __restrict__ opart,
    float2* __restrict__ mlpart,
    int S, int H)
{
    __shared__ __align__(16) half_t Ks[64 * 64];        // [kv][d]   (swizzled)
    __shared__ __align__(16) half_t Vs[64 * 64];        // [d][kv]   (swizzled)
    __shared__ __align__(16) half_t Ps[4 * 32 * 64];    // per-wave P (swizzled)

    const float LOG2E = 1.44269504f;
    const float SCL2  = 0.125f * 1.44269504f;   // 1/sqrt(64) * log2(e)

    const int qt = blockIdx.x, h = blockIdx.y, z = blockIdx.z;
    const int b = z >> 1, hf = z & 1;
    const int tid = threadIdx.x, w = tid >> 6, lane = tid & 63;
    const int g = lane >> 4, ml = lane & 15, m7 = ml & 7;
    const int NHloc = gridDim.y;
    const int BNHS = 2 * NHloc * S;   // B*NH*S (B=2)

    const int q0 = qt * 128 + w * 32;
    const half_t* Qg = Q  + ((size_t)(b * S + q0)) * H + h * 64;
    const half_t* Kg = Kq + ((size_t)b * S) * H + h * 64;
    const half_t* Vg = Vt + ((size_t)b * H + h * 64) * (size_t)S;
    const float*  mk = mask + (size_t)b * S;

    half8 qf[2][2];
#pragma unroll
    for (int qi = 0; qi < 2; qi++)
#pragma unroll
        for (int kk = 0; kk < 2; kk++)
            qf[qi][kk] = *(const half8*)(Qg + (size_t)(qi * 16 + ml) * H + kk * 32 + g * 8);

    float m_[2] = {-1e30f, -1e30f}, l_[2] = {0.f, 0.f};
    f32x4 o[2][4];
#pragma unroll
    for (int qi = 0; qi < 2; qi++)
#pragma unroll
        for (int df = 0; df < 4; df++) o[qi][df] = zero4();

    half_t* Pw = &Ps[w * 32 * 64];
    const int srow = tid >> 3;            // staging row (round t adds 32)
    const int sc   = tid & 7;             // phys 16B chunk within row

    const int kvbeg = hf * (S >> 1), kvend = kvbeg + (S >> 1);
    for (int kv0 = kvbeg; kv0 < kvend; kv0 += 64) {
        __syncthreads();
#pragma unroll
        for (int t = 0; t < 2; t++) {
            int row = t * 32 + srow;
            int ck  = sc ^ (row & 7);     // source chunk for phys chunk sc
            gl_lds16(Kg + (size_t)(kv0 + row) * H + ck * 8, &Ks[(t * 256 + w * 64) * 8]);
            gl_lds16(Vg + (size_t)row * S + kv0 + ck * 8,   &Vs[(t * 256 + w * 64) * 8]);
        }
        __syncthreads();

        f32x4 s[2][4];
#pragma unroll
        for (int kvf = 0; kvf < 4; kvf++) {
            half8 k0 = lds_frag(&Ks[(kvf * 16 + ml) * 64 + ((0 + g) ^ m7) * 8]);
            half8 k1 = lds_frag(&Ks[(kvf * 16 + ml) * 64 + ((4 + g) ^ m7) * 8]);
            s[0][kvf] = __builtin_amdgcn_mfma_f32_16x16x32_f16(k0, qf[0][0], zero4(), 0, 0, 0);
            s[0][kvf] = __builtin_amdgcn_mfma_f32_16x16x32_f16(k1, qf[0][1], s[0][kvf], 0, 0, 0);
            s[1][kvf] = __builtin_amdgcn_mfma_f32_16x16x32_f16(k0, qf[1][0], zero4(), 0, 0, 0);
            s[1][kvf] = __builtin_amdgcn_mfma_f32_16x16x32_f16(k1, qf[1][1], s[1][kvf], 0, 0, 0);
        }
        // ---- scale + mask, log2 domain
#pragma unroll
        for (int kvf = 0; kvf < 4; kvf++) {
            float4 mv = *(const float4*)(mk + kv0 + kvf * 16 + g * 4);
#pragma unroll
            for (int qi = 0; qi < 2; qi++) {
                s[qi][kvf][0] = s[qi][kvf][0] * SCL2 + mv.x * LOG2E;
                s[qi][kvf][1] = s[qi][kvf][1] * SCL2 + mv.y * LOG2E;
                s[qi][kvf][2] = s[qi][kvf][2] * SCL2 + mv.z * LOG2E;
                s[qi][kvf][3] = s[qi][kvf][3] * SCL2 + mv.w * LOG2E;
            }
        }
        // ---- online softmax with defer-max (THR = 8 nats = 11.5 in log2)
        float alpha[2];
        bool  defer[2];
#pragma unroll
        for (int qi = 0; qi < 2; qi++) {
            float mx = -1e30f;
#pragma unroll
            for (int kvf = 0; kvf < 4; kvf++)
#pragma unroll
                for (int r = 0; r < 4; r++) mx = fmaxf(mx, s[qi][kvf][r]);
            mx = fmaxf(mx, __shfl_xor(mx, 16));
            mx = fmaxf(mx, __shfl_xor(mx, 32));
            defer[qi] = __all(mx <= m_[qi] + 11.5f);   // wave-uniform
            float mnew, al;
            if (defer[qi]) { mnew = m_[qi]; al = 1.f; }
            else           { mnew = fmaxf(m_[qi], mx); al = fexp2(m_[qi] - mnew); }
            alpha[qi] = al;
            m_[qi] = mnew;
            float ps = 0.f;
#pragma unroll
            for (int kvf = 0; kvf < 4; kvf++)
#pragma unroll
                for (int r = 0; r < 4; r++) {
                    float pv = fexp2(s[qi][kvf][r] - mnew);
                    s[qi][kvf][r] = pv; ps += pv;
                }
            ps += __shfl_xor(ps, 16);
            ps += __shfl_xor(ps, 32);
            l_[qi] = l_[qi] * al + ps;
#pragma unroll
            for (int kvf = 0; kvf < 4; kvf++) {
                half4v pk;
#pragma unroll
                for (int r = 0; r < 4; r++) pk[r] = (half_t)s[qi][kvf][r];
                *(half4v*)(Pw + (qi * 16 + ml) * 64 +
                           (((kvf * 2 + (g >> 1)) ^ m7) * 8) + (g & 1) * 4) = pk;
            }
        }
        // ---- O rescale, skipped when deferred (wave-uniform branches)
#pragma unroll
        for (int qi = 0; qi < 2; qi++) {
            if (!defer[qi]) {
#pragma unroll
                for (int r = 0; r < 4; r++) {
                    float a = __shfl(alpha[qi], (lane & 48) + g * 4 + r);
#pragma unroll
                    for (int df = 0; df < 4; df++) o[qi][df][r] *= a;
                }
            }
        }
#pragma unroll
        for (int kk = 0; kk < 2; kk++) {
            half8 pa0 = lds_frag(&Pw[(ml)      * 64 + ((kk * 4 + g) ^ m7) * 8]);
            half8 pa1 = lds_frag(&Pw[(16 + ml) * 64 + ((kk * 4 + g) ^ m7) * 8]);
#pragma unroll
            for (int df = 0; df < 4; df++) {
                half8 vb = lds_frag(&Vs[(df * 16 + ml) * 64 + ((kk * 4 + g) ^ m7) * 8]);
                o[0][df] = __builtin_amdgcn_mfma_f32_16x16x32_f16(pa0, vb, o[0][df], 0, 0, 0);
                o[1][df] = __builtin_amdgcn_mfma_f32_16x16x32_f16(pa1, vb, o[1][df], 0, 0, 0);
            }
        }
    }

    // write partials: unnormalized o (fp16) + per-row (m,l), m in log2 domain
    const size_t rowbase = (size_t)hf * BNHS + ((size_t)(b * NHloc + h)) * S + q0;
#pragma unroll
    for (int qi = 0; qi < 2; qi++) {
#pragma unroll
        for (int r = 0; r < 4; r++) {
            size_t ro = (rowbase + qi * 16 + g * 4 + r) * 64;
#pragma unroll
            for (int df = 0; df < 4; df++)
                opart[ro + df * 16 + ml] = (half_t)o[qi][df][r];
        }
    }
    if (g == 0) {
#pragma unroll
        for (int qi = 0; qi < 2; qi++)
            mlpart[rowbase + qi * 16 + ml] = make_float2(m_[qi], l_[qi]);
    }
}

// ---------------------------------------------------------------------------
// Merge the two kv-half partials -> ctx [B*S][H] fp16. m is log2-domain.
// ---------------------------------------------------------------------------
__global__ __launch_bounds__(256) void flash_merge(
    const half_t* __restrict__ opart,
    const float2* __restrict__ mlpart,
    half_t* __restrict__ ctx)
{
    int gid = blockIdx.x * 256 + threadIdx.x;   // 65536*16
    int row = gid >> 4, dg = (gid & 15) * 4;
    float2 a = mlpart[row], c = mlpart[65536 + row];
    float m  = fmaxf(a.x, c.x);
    float w1 = fexp2(a.x - m), w2 = fexp2(c.x - m);
    float inv = 1.f / (w1 * a.y + w2 * c.y);
    half4v o1 = *(const half4v*)&opart[(size_t)row * 64 + dg];
    half4v o2 = *(const half4v*)&opart[(size_t)(65536 + row) * 64 + dg];
    int b = row >> 15, hq = row & 32767;
    int h = hq >> 11, q = hq & 2047;
    half4v o;
#pragma unroll
    for (int i = 0; i < 4; i++)
        o[i] = (half_t)((w1 * (float)o1[i] + w2 * (float)o2[i]) * inv);
    *(half4v*)&ctx[((size_t)(b * 2048 + q)) * 1024 + h * 64 + dg] = o;
}

// ---------------------------------------------------------------------------
// W[K][N] fp32 -> Wt[N][K] fp16 (32x32 tiles), batched over grid.z
// ---------------------------------------------------------------------------
__global__ __launch_bounds__(256) void transpose_cast(
    const float* __restrict__ W, half_t* __restrict__ Wt, int Kd, int Nd)
{
    __shared__ float tile[32][33];
    size_t zoff = (size_t)blockIdx.z * Kd * Nd;
    const float* Wz = W + zoff;
    half_t* Wtz = Wt + zoff;
    int n0 = blockIdx.x * 32, k0 = blockIdx.y * 32;
    int tx = threadIdx.x & 31, ty = threadIdx.x >> 5;
#pragma unroll
    for (int j = 0; j < 4; j++)
        tile[ty + j * 8][tx] = Wz[(size_t)(k0 + ty + j * 8) * Nd + n0 + tx];
    __syncthreads();
#pragma unroll
    for (int j = 0; j < 4; j++)
        Wtz[(size_t)(n0 + ty + j * 8) * Kd + k0 + tx] = (half_t)tile[tx][ty + j * 8];
}

// Q/K/V weights -> per-layer fused [l][3][H][H] transposed fp16
__global__ __launch_bounds__(256) void transpose_qkv(
    const float* __restrict__ Wq, const float* __restrict__ Wk,
    const float* __restrict__ Wv, half_t* __restrict__ WT)
{
    __shared__ float tile[32][33];
    int z = blockIdx.z, l = z / 3, which = z % 3;
    const float* W = ((which == 0) ? Wq : (which == 1) ? Wk : Wv) + (size_t)l * 1024 * 1024;
    half_t* D = WT + ((size_t)l * 3 + which) * 1024 * 1024;
    int n0 = blockIdx.x * 32, k0 = blockIdx.y * 32;
    int tx = threadIdx.x & 31, ty = threadIdx.x >> 5;
#pragma unroll
    for (int j = 0; j < 4; j++)
        tile[ty + j * 8][tx] = W[(size_t)(k0 + ty + j * 8) * 1024 + n0 + tx];
    __syncthreads();
#pragma unroll
    for (int j = 0; j < 4; j++)
        D[(size_t)(n0 + ty + j * 8) * 1024 + k0 + tx] = (half_t)tile[tx][ty + j * 8];
}

__global__ __launch_bounds__(256) void cast_f32_f16(
    const float* __restrict__ in, half_t* __restrict__ out)
{
    int i = blockIdx.x * 256 + threadIdx.x;
    float4 v = ((const float4*)in)[i];
    half4v o; o[0] = (half_t)v.x; o[1] = (half_t)v.y; o[2] = (half_t)v.z; o[3] = (half_t)v.w;
    *(half4v*)(out + (size_t)i * 4) = o;
}

// ---------------------------------------------------------------------------
// LayerNorm over H=1024; emits fp32 (residual path) + fp16 (next GEMM input)
// ---------------------------------------------------------------------------
__global__ __launch_bounds__(256) void layernorm_k(
    const float* __restrict__ in,
    const float* __restrict__ gam, const float* __restrict__ bet,
    float* __restrict__ outf, half_t* __restrict__ outh)
{
    int row = blockIdx.x, tid = threadIdx.x;
    const float4 v = ((const float4*)(in + (size_t)row * 1024))[tid];
    float s = v.x + v.y + v.z + v.w;
    float q = v.x * v.x + v.y * v.y + v.z * v.z + v.w * v.w;
    for (int off = 32; off; off >>= 1) { s += __shfl_down(s, off); q += __shfl_down(q, off); }
    __shared__ float ss[4], sq[4];
    int w = tid >> 6;
    if ((tid & 63) == 0) { ss[w] = s; sq[w] = q; }
    __syncthreads();
    float S_ = ss[0] + ss[1] + ss[2] + ss[3];
    float Q_ = sq[0] + sq[1] + sq[2] + sq[3];
    float mean = S_ * (1.f / 1024.f);
    float var  = Q_ * (1.f / 1024.f) - mean * mean;
    float rstd = rsqrtf(var + 1e-5f);
    float4 gm = ((const float4*)gam)[tid];
    float4 bt = ((const float4*)bet)[tid];
    float y0 = (v.x - mean) * rstd * gm.x + bt.x;
    float y1 = (v.y - mean) * rstd * gm.y + bt.y;
    float y2 = (v.z - mean) * rstd * gm.z + bt.z;
    float y3 = (v.w - mean) * rstd * gm.w + bt.w;
    ((float4*)(outf + (size_t)row * 1024))[tid] = make_float4(y0, y1, y2, y3);
    half4v oh; oh[0] = (half_t)y0; oh[1] = (half_t)y1; oh[2] = (half_t)y2; oh[3] = (half_t)y3;
    *(half4v*)(outh + (size_t)row * 1024 + tid * 4) = oh;
}

// ---------------------------------------------------------------------------
// LayerNorm fused with split-K=2 reduce: x = part0 + part1 + bias + res.
// part: [2][M][1024] f32, M=4096.
// ---------------------------------------------------------------------------
__global__ __launch_bounds__(256) void layernorm_sk2(
    const float* __restrict__ part,
    const float* __restrict__ bias,
    const float* __restrict__ res,
    const float* __restrict__ gam, const float* __restrict__ bet,
    float* __restrict__ outf, half_t* __restrict__ outh)
{
    const size_t SP = (size_t)4096 * 1024;
    int row = blockIdx.x, tid = threadIdx.x;
    size_t o = (size_t)row * 1024 + tid * 4;
    float4 v0 = *(const float4*)(part + o);
    float4 v1 = *(const float4*)(part + SP + o);
    float4 rv = *(const float4*)(res + o);
    float4 bb = ((const float4*)bias)[tid];
    float x0 = v0.x + v1.x + bb.x + rv.x;
    float x1 = v0.y + v1.y + bb.y + rv.y;
    float x2 = v0.z + v1.z + bb.z + rv.z;
    float x3 = v0.w + v1.w + bb.w + rv.w;

    float s = x0 + x1 + x2 + x3;
    float q = x0 * x0 + x1 * x1 + x2 * x2 + x3 * x3;
    for (int off = 32; off; off >>= 1) { s += __shfl_down(s, off); q += __shfl_down(q, off); }
    __shared__ float ss[4], sq[4];
    int w = tid >> 6;
    if ((tid & 63) == 0) { ss[w] = s; sq[w] = q; }
    __syncthreads();
    float S_ = ss[0] + ss[1] + ss[2] + ss[3];
    float Q_ = sq[0] + sq[1] + sq[2] + sq[3];
    float mean = S_ * (1.f / 1024.f);
    float var  = Q_ * (1.f / 1024.f) - mean * mean;
    float rstd = rsqrtf(var + 1e-5f);
    float4 gm = ((const float4*)gam)[tid];
    float4 bt = ((const float4*)bet)[tid];
    float y0 = (x0 - mean) * rstd * gm.x + bt.x;
    float y1 = (x1 - mean) * rstd * gm.y + bt.y;
    float y2 = (x2 - mean) * rstd * gm.z + bt.z;
    float y3 = (x3 - mean) * rstd * gm.w + bt.w;
    ((float4*)(outf + (size_t)row * 1024))[tid] = make_float4(y0, y1, y2, y3);
    half4v oh; oh[0] = (half_t)y0; oh[1] = (half_t)y1; oh[2] = (half_t)y2; oh[3] = (half_t)y3;
    *(half4v*)(outh + (size_t)row * 1024 + tid * 4) = oh;
}

// ---------------------------------------------------------------------------
extern "C" void kernel_launch(void* const* d_in, const int* in_sizes, int n_in,
                              void* d_out, int out_size, void* d_ws, size_t ws_size,
                              hipStream_t stream)
{
    const int Lc = 2, Bb = 2, S = 2048, Hh = 1024, NH = 16, FF = 4096;
    const int M = Bb * S;  // 4096

    const float* hs   = (const float*)d_in[0];
    const float* mask = (const float*)d_in[1];
    const float* Wq   = (const float*)d_in[2];  const float* bq  = (const float*)d_in[3];
    const float* Wk   = (const float*)d_in[4];  const float* bk  = (const float*)d_in[5];
    const float* Wv   = (const float*)d_in[6];  const float* bv  = (const float*)d_in[7];
    const float* Wao  = (const float*)d_in[8];  const float* bao = (const float*)d_in[9];
    const float* g1   = (const float*)d_in[10]; const float* b1  = (const float*)d_in[11];
    const float* Wi   = (const float*)d_in[12]; const float* bi  = (const float*)d_in[13];
    const float* Wo   = (const float*)d_in[14]; const float* bo  = (const float*)d_in[15];
    const float* g2   = (const float*)d_in[16]; const float* b2  = (const float*)d_in[17];

    char* p = (char*)d_ws;
    auto take = [&](size_t bytes) { char* r = p; p += (bytes + 255) & ~(size_t)255; return r; };

    half_t* WqkvT = (half_t*)take((size_t)Lc * 3 * Hh * Hh * 2);   // 12 MB
    half_t* WaoT  = (half_t*)take((size_t)Lc * Hh * Hh * 2);       //  4 MB
    half_t* WiT   = (half_t*)take((size_t)Lc * Hh * FF * 2);       // 16 MB
    half_t* WoT   = (half_t*)take((size_t)Lc * FF * Hh * 2);       // 16 MB
    half_t* xb    = (half_t*)take((size_t)M * Hh * 2);             //  8 MB
    half_t* Qb    = (half_t*)take((size_t)M * Hh * 2);             //  8 MB
    half_t* Kb2   = (half_t*)take((size_t)M * Hh * 2);             //  8 MB
    half_t* Vtb   = (half_t*)take((size_t)M * Hh * 2);             //  8 MB
    (void)          take((size_t)M * Hh * 2);                      //  8 MB pad (h1 span)
    half_t* h1    = Qb;   // FFN hidden [M][FF] fp16 reuses Qb..pad (32 MB)
    float*  t0    = (float*)take((size_t)M * Hh * 4);              // 16 MB
    float*  x1f   = (float*)take((size_t)M * Hh * 4);              // 16 MB
    half_t* x1b   = (half_t*)take((size_t)M * Hh * 2);             //  8 MB
    float*  part  = (float*)take((size_t)2 * M * Hh * 4);          // 32 MB splitK partials

    // flash partials alias dead-at-attention buffers:
    half_t* opart  = (half_t*)t0;    // 2*65536*64*2 B = 16.78 MB == sizeof(t0)
    float2* mlpart = (float2*)x1b;   // 2*65536*8 B = 1 MB

    dim3 tb(256);

    transpose_qkv<<<dim3(32, 32, Lc * 3), tb, 0, stream>>>(Wq, Wk, Wv, WqkvT);
    transpose_cast<<<dim3(32, 32, Lc), tb, 0, stream>>>(Wao, WaoT, Hh, Hh);
    transpose_cast<<<dim3(FF / 32, 32, Lc), tb, 0, stream>>>(Wi, WiT, Hh, FF);
    transpose_cast<<<dim3(32, FF / 32, Lc), tb, 0, stream>>>(Wo, WoT, FF, Hh);
    cast_f32_f16<<<dim3(M * Hh / 1024), tb, 0, stream>>>(hs, xb);

    const float* xres = hs;
    for (int l = 0; l < Lc; l++) {
        const half_t* WqkvTl = WqkvT + (size_t)l * 3 * Hh * Hh;
        const half_t* WaoTl  = WaoT  + (size_t)l * Hh * Hh;
        const half_t* WiTl   = WiT   + (size_t)l * Hh * FF;
        const half_t* WoTl   = WoT   + (size_t)l * FF * Hh;

        gemm256_qkv<<<dim3(3072 / 256, M / 256), dim3(512), 0, stream>>>(
            xb, WqkvTl, bq + l * Hh, bk + l * Hh, bv + l * Hh, Qb, Kb2, Vtb, M, Hh);

        flash_attn<<<dim3(S / 128, NH, Bb * 2), tb, 0, stream>>>(
            Qb, Kb2, Vtb, mask, opart, mlpart, S, Hh);
        flash_merge<<<dim3(Bb * NH * S * 16 / 256), tb, 0, stream>>>(opart, mlpart, xb);

        gemm_bt64<<<dim3(Hh / 64, M / 128), tb, 0, stream>>>(
            xb, WaoTl, bao + l * Hh, xres, t0, M, Hh, Hh);
        layernorm_k<<<dim3(M), tb, 0, stream>>>(t0, g1 + l * Hh, b1 + l * Hh, x1f, x1b);

        gemm256_bt<<<dim3(FF / 256, M / 256), dim3(512), 0, stream>>>(
            x1b, WiTl, bi + l * FF, nullptr, h1, M, FF, Hh, MODE_GELU);

        // FFN2: split-K=2 through the 128x64 tile (grid 1024 = 4/CU),
        // reduce + bias + residual fused into layernorm_sk2.
        gemm_bt64_sk<<<dim3(Hh / 64, M / 128, 2), tb, 0, stream>>>(
            h1, WoTl, part, M, Hh, FF, FF / 2);

        float* outf = (l == Lc - 1) ? (float*)d_out : x1f;
        layernorm_sk2<<<dim3(M), tb, 0, stream>>>(
            part, bo + l * Hh, x1f, g2 + l * Hh, b2 + l * Hh, outf, xb);
        xres = x1f;
    }
}

// Round 9
// 681.586 us; speedup vs baseline: 1.0774x; 1.0774x over previous
//
#include <hip/hip_runtime.h>

typedef _Float16 half_t;
typedef _Float16 half8  __attribute__((ext_vector_type(8)));
typedef _Float16 half4v __attribute__((ext_vector_type(4)));
typedef float    f32x4  __attribute__((ext_vector_type(4)));

#define AS1 __attribute__((address_space(1)))
#define AS3 __attribute__((address_space(3)))

#define MODE_H16  0   // store fp16
#define MODE_F32R 1   // store fp32 = acc + bias + residual
#define MODE_GELU 2   // store fp16 = gelu(acc + bias)

__device__ __forceinline__ f32x4 zero4() {
    f32x4 z; z[0] = 0.f; z[1] = 0.f; z[2] = 0.f; z[3] = 0.f; return z;
}

__device__ __forceinline__ half8 lds_frag(const half_t* p) {
    union { uint4 u; half8 h; } c;
    c.u = *(const uint4*)p;
    return c.h;
}

// fast tanh-GELU: v*sigmoid(1.59577(v+0.044715 v^3)); |err| ~3e-4
__device__ __forceinline__ float gelu_f(float v) {
    float t = v * v;
    float u = v * (1.595769122f + 0.0713548163f * t);
    return v / (1.f + __expf(-u));
}

__device__ __forceinline__ float fexp2(float x) {
    return __builtin_amdgcn_exp2f(x);
}

// async global->LDS, 16B/lane; LDS dest is wave-uniform base + lane*16
__device__ __forceinline__ void gl_lds16(const half_t* g, half_t* l) {
    __builtin_amdgcn_global_load_lds(
        (AS1 unsigned int*)(unsigned long long)(const void*)g,
        (AS3 unsigned int*)l,
        16, 0, 0);
}

// ---------------------------------------------------------------------------
// Swizzle convention (shared by all tiles): logical 8-half chunk c of row r
// lives at phys chunk c^(r&7).  Staging lane at phys chunk p of row r reads
// source chunk p^(r&7); reader of logical chunk c applies the same XOR.
// ---------------------------------------------------------------------------

// ===========================================================================
// 256x256 4-phase GEMM core (proven config: rounds 1/2/4, 683-684 us).
// BM=BN=256, BK=64, 512 thr = 8 waves (2M x 4N), per-wave out 128x64.
// LDS 128 KiB: A/B each 2 bufs x [256][64] half.
// ===========================================================================

__device__ __forceinline__ void stage_half(
    const half_t* __restrict__ G, half_t* L, int K, int srow, int sck, int w)
{
    // 16 KB half-tile = 128 rows x 64 halfs; 2 gl_lds per thread.
    gl_lds16(G + (size_t)srow * K + sck,        L + w * 512);
    gl_lds16(G + (size_t)(64 + srow) * K + sck, L + 4096 + w * 512);
}

#define LDA(MH)                                                              \
    _Pragma("unroll")                                                        \
    for (int m = 0; m < 4; m++) {                                            \
        af[m][0] = lds_frag(&Ad[abase + (MH) * 4096 + m * 1024 + c0]);       \
        af[m][1] = lds_frag(&Ad[abase + (MH) * 4096 + m * 1024 + c1]);       \
    }

#define LDB(NH)                                                              \
    _Pragma("unroll")                                                        \
    for (int n = 0; n < 2; n++) {                                            \
        bf[NH][n][0] = lds_frag(&Bd[bbase + (NH) * 2048 + n * 1024 + c0]);   \
        bf[NH][n][1] = lds_frag(&Bd[bbase + (NH) * 2048 + n * 1024 + c1]);   \
    }

#define MFMA_Q(MH, NH)                                                       \
    _Pragma("unroll")                                                        \
    for (int m = 0; m < 4; m++)                                              \
        _Pragma("unroll")                                                    \
        for (int n = 0; n < 2; n++) {                                        \
            acc[(MH)*4 + m][(NH)*2 + n] =                                    \
                __builtin_amdgcn_mfma_f32_16x16x32_f16(                      \
                    af[m][0], bf[NH][n][0], acc[(MH)*4 + m][(NH)*2 + n],     \
                    0, 0, 0);                                                \
            acc[(MH)*4 + m][(NH)*2 + n] =                                    \
                __builtin_amdgcn_mfma_f32_16x16x32_f16(                      \
                    af[m][1], bf[NH][n][1], acc[(MH)*4 + m][(NH)*2 + n],     \
                    0, 0, 0);                                                \
        }

__device__ __forceinline__ void mfma_core256(
    const half_t* __restrict__ Ag, const half_t* __restrict__ Bg, int K,
    half_t* As, half_t* Bs, f32x4 (&acc)[8][4])
{
    const int tid  = threadIdx.x;
    const int w    = tid >> 6, lane = tid & 63;
    const int wm   = w >> 2, wn = w & 3;
    const int g    = lane >> 4, ml = lane & 15, m7 = ml & 7;
    const int srow = tid >> 3;
    const int sck  = ((tid & 7) ^ (srow & 7)) * 8;

#pragma unroll
    for (int i = 0; i < 8; i++)
#pragma unroll
        for (int j = 0; j < 4; j++) acc[i][j] = zero4();

    const int abase = (wm * 128 + ml) * 64;       // wave's A row base in LDS
    const int bbase = (wn * 64 + ml) * 64;        // wave's B row base in LDS
    const int c0 = (g ^ m7) * 8, c1 = ((4 + g) ^ m7) * 8;   // kk=0/1 chunks

    // prologue: tile 0 -> buf 0 (8 gl_lds), full drain once.
    stage_half(Ag, As, K, srow, sck, w);
    stage_half(Ag + (size_t)128 * K, As + 8192, K, srow, sck, w);
    stage_half(Bg, Bs, K, srow, sck, w);
    stage_half(Bg + (size_t)128 * K, Bs + 8192, K, srow, sck, w);
    asm volatile("s_waitcnt vmcnt(0)" ::: "memory");
    __builtin_amdgcn_s_barrier();

    const int NT = K >> 6;
    half8 af[4][2];
    half8 bf[2][2][2];

    for (int t = 0; t < NT; ++t) {
        half_t* Ad = As + (t & 1) * 16384;
        half_t* Bd = Bs + (t & 1) * 16384;
        half_t* An = As + ((t + 1) & 1) * 16384;
        half_t* Bn = Bs + ((t + 1) & 1) * 16384;
        const half_t* Agn = Ag + (t + 1) * 64;
        const half_t* Bgn = Bg + (t + 1) * 64;
        const bool pf = (t + 1 < NT);

        // ---- P1: q(0,0)
        LDA(0)
        LDB(0)
        if (pf) {
            stage_half(Agn, An, K, srow, sck, w);
            stage_half(Agn + (size_t)128 * K, An + 8192, K, srow, sck, w);
        }
        __builtin_amdgcn_s_barrier();
        __builtin_amdgcn_s_setprio(1);
        MFMA_Q(0, 0)
        __builtin_amdgcn_s_setprio(0);
        __builtin_amdgcn_s_barrier();

        // ---- P2: q(0,1)
        LDB(1)
        if (pf) {
            stage_half(Bgn, Bn, K, srow, sck, w);
            stage_half(Bgn + (size_t)128 * K, Bn + 8192, K, srow, sck, w);
        }
        __builtin_amdgcn_s_barrier();
        __builtin_amdgcn_s_setprio(1);
        MFMA_Q(0, 1)
        __builtin_amdgcn_s_setprio(0);
        __builtin_amdgcn_s_barrier();

        // ---- P3: q(1,1)
        LDA(1)
        __builtin_amdgcn_s_barrier();
        __builtin_amdgcn_s_setprio(1);
        MFMA_Q(1, 1)
        __builtin_amdgcn_s_setprio(0);
        __builtin_amdgcn_s_barrier();

        // ---- P4: q(1,0); counted drain of P1/P2 prefetches; tile boundary
        __builtin_amdgcn_s_setprio(1);
        MFMA_Q(1, 0)
        __builtin_amdgcn_s_setprio(0);
        asm volatile("s_waitcnt vmcnt(0)" ::: "memory");
        __builtin_amdgcn_s_barrier();
    }
}

// ---------------------------------------------------------------------------
// C[M,N] = A[M,K] @ Bt[N,K]^T + bias, fused epilogues. 256x256 tile.
// Epilogue: nj INNERMOST so each (mi,r) writes 128B contiguous per row
// back-to-back -> no partial-line L2 evictions (fix for 2.4x WRITE_SIZE).
// ---------------------------------------------------------------------------
__global__ __launch_bounds__(512, 2) void gemm256_bt(
    const half_t* __restrict__ A,
    const half_t* __restrict__ Bt,
    const float*  __restrict__ bias,
    const float*  __restrict__ res,
    void* __restrict__ out,
    int M, int N, int K, int mode)
{
    __shared__ __align__(16) half_t As[2 * 16384];
    __shared__ __align__(16) half_t Bs[2 * 16384];

    const int m0 = blockIdx.y * 256, n0 = blockIdx.x * 256;
    f32x4 acc[8][4];
    mfma_core256(A + (size_t)m0 * K, Bt + (size_t)n0 * K, K, As, Bs, acc);

    const int tid = threadIdx.x;
    const int w   = tid >> 6, lane = tid & 63;
    const int wm  = w >> 2, wn = w & 3;
    const int g   = lane >> 4, ml = lane & 15;
    const int gm0 = m0 + wm * 128, gn0 = n0 + wn * 64;

    float bv4[4];
#pragma unroll
    for (int nj = 0; nj < 4; nj++) bv4[nj] = bias[gn0 + nj * 16 + ml];

#pragma unroll
    for (int mi = 0; mi < 8; mi++) {
#pragma unroll
        for (int r = 0; r < 4; r++) {
            int row = gm0 + mi * 16 + g * 4 + r;
            size_t rb = (size_t)row * N;
#pragma unroll
            for (int nj = 0; nj < 4; nj++) {
                int col = gn0 + nj * 16 + ml;
                float v = acc[mi][nj][r] + bv4[nj];
                size_t idx = rb + col;
                if (mode == MODE_F32R) {
                    ((float*)out)[idx] = v + res[idx];
                } else if (mode == MODE_GELU) {
                    ((half_t*)out)[idx] = (half_t)gelu_f(v);
                } else {
                    ((half_t*)out)[idx] = (half_t)v;
                }
            }
        }
    }
}

// ---------------------------------------------------------------------------
// Fused QKV GEMM, 256x256 tile: N=3072 (Wq|Wk|Wv transposed, contiguous).
// Q/K epilogue reordered (nj innermost) like gemm256_bt.
// ---------------------------------------------------------------------------
__global__ __launch_bounds__(512, 2) void gemm256_qkv(
    const half_t* __restrict__ A,
    const half_t* __restrict__ Bt,
    const float*  __restrict__ bq,
    const float*  __restrict__ bk,
    const float*  __restrict__ bv,
    half_t* __restrict__ Qo, half_t* __restrict__ Ko, half_t* __restrict__ Vto,
    int M, int K)
{
    __shared__ __align__(16) half_t As[2 * 16384];
    __shared__ __align__(16) half_t Bs[2 * 16384];

    const int m0 = blockIdx.y * 256, n0 = blockIdx.x * 256;
    f32x4 acc[8][4];
    mfma_core256(A + (size_t)m0 * K, Bt + (size_t)n0 * K, K, As, Bs, acc);

    const int tid = threadIdx.x;
    const int w   = tid >> 6, lane = tid & 63;
    const int wm  = w >> 2, wn = w & 3;
    const int g   = lane >> 4, ml = lane & 15;

    const int seg   = n0 >> 10;                 // block-uniform: 0=Q,1=K,2=V
    const int nbase = (n0 & 1023) + wn * 64;
    const float* bias = (seg == 0) ? bq : (seg == 1) ? bk : bv;
    const int gm0 = m0 + wm * 128;

    float bv4[4];
#pragma unroll
    for (int nj = 0; nj < 4; nj++) bv4[nj] = bias[nbase + nj * 16 + ml];

    if (seg < 2) {
        half_t* O = (seg == 0) ? Qo : Ko;
#pragma unroll
        for (int mi = 0; mi < 8; mi++) {
#pragma unroll
            for (int r = 0; r < 4; r++) {
                size_t rb = (size_t)(gm0 + mi * 16 + g * 4 + r) * 1024;
#pragma unroll
                for (int nj = 0; nj < 4; nj++)
                    O[rb + nbase + nj * 16 + ml] =
                        (half_t)(acc[mi][nj][r] + bv4[nj]);
            }
        }
    } else {
#pragma unroll
        for (int nj = 0; nj < 4; nj++) {
            int col = nbase + nj * 16 + ml;
            float bvv = bv4[nj];
#pragma unroll
            for (int mi = 0; mi < 8; mi++) {
                int rowb = gm0 + mi * 16 + g * 4;
                int bb = rowb >> 11, sl = rowb & 2047;       // S=2048
                half4v v4;
#pragma unroll
                for (int r = 0; r < 4; r++) v4[r] = (half_t)(acc[mi][nj][r] + bvv);
                *(half4v*)&Vto[((size_t)bb * 1024 + col) * 2048 + sl] = v4;
            }
        }
    }
}

// ---------------------------------------------------------------------------
// 128x64-tile GEMM for N=1024 cases. BK=64. MODE_F32R only.
// Epilogue reordered: j innermost (contiguous 128B res-read + out-write).
// ---------------------------------------------------------------------------
__global__ __launch_bounds__(256) void gemm_bt64(
    const half_t* __restrict__ A,
    const half_t* __restrict__ Bt,
    const float*  __restrict__ bias,
    const float*  __restrict__ res,
    float* __restrict__ out,
    int M, int N, int K)
{
    __shared__ __align__(16) half_t As[128 * 64];
    __shared__ __align__(16) half_t Bs[64 * 64];

    const int tid  = threadIdx.x;
    const int w    = tid >> 6, lane = tid & 63;
    const int m0   = blockIdx.y * 128, n0 = blockIdx.x * 64;
    const int g    = lane >> 4, ml = lane & 15, m7 = ml & 7;
    const int mo   = w * 32;
    const int r8   = lane >> 3;
    const int sck  = ((lane & 7) ^ (r8 & 7)) * 8;

    f32x4 acc[2][4];
#pragma unroll
    for (int i = 0; i < 2; i++)
#pragma unroll
        for (int j = 0; j < 4; j++) acc[i][j] = zero4();

    const half_t* Ag = A  + (size_t)m0 * K;
    const half_t* Bg = Bt + (size_t)n0 * K;

    for (int k0 = 0; k0 < K; k0 += 64) {
        __syncthreads();
#pragma unroll
        for (int i = 0; i < 4; i++) {
            int t = w * 4 + i;
            gl_lds16(Ag + (size_t)(t * 8 + r8) * K + k0 + sck, &As[t * 512]);
        }
#pragma unroll
        for (int i = 0; i < 2; i++) {
            int t = w * 2 + i;
            gl_lds16(Bg + (size_t)(t * 8 + r8) * K + k0 + sck, &Bs[t * 512]);
        }
        __syncthreads();
#pragma unroll
        for (int kk = 0; kk < 2; kk++) {
            const int co = ((kk * 4 + g) ^ m7) * 8;
            half8 af[2], bf[4];
#pragma unroll
            for (int i = 0; i < 2; i++) af[i] = lds_frag(&As[(mo + i * 16 + ml) * 64 + co]);
#pragma unroll
            for (int j = 0; j < 4; j++) bf[j] = lds_frag(&Bs[(j * 16 + ml) * 64 + co]);
#pragma unroll
            for (int i = 0; i < 2; i++)
#pragma unroll
                for (int j = 0; j < 4; j++)
                    acc[i][j] = __builtin_amdgcn_mfma_f32_16x16x32_f16(af[i], bf[j], acc[i][j], 0, 0, 0);
        }
    }

    const int gm0 = m0 + mo;
    float bv4[4];
#pragma unroll
    for (int j = 0; j < 4; j++) bv4[j] = bias[n0 + j * 16 + ml];
#pragma unroll
    for (int i = 0; i < 2; i++) {
#pragma unroll
        for (int r = 0; r < 4; r++) {
            int row = gm0 + i * 16 + g * 4 + r;
            size_t rb = (size_t)row * N;
#pragma unroll
            for (int j = 0; j < 4; j++) {
                size_t idx = rb + n0 + j * 16 + ml;
                out[idx] = acc[i][j][r] + bv4[j] + res[idx];
            }
        }
    }
}

// ---------------------------------------------------------------------------
// Flash attention v4b: kv-split x2, single-buffer gl_lds staging, log2
// softmax + defer-max.  (Best-known flash config: rounds 1/4/5.)
// opart: [2][B*NH*S][64] fp16 ; mlpart: [2][B*NH*S] float2 (m in log2).
// ---------------------------------------------------------------------------
__global__ __launch_bounds__(256, 4) void flash_attn(
    const half_t* __restrict__ Q,
    const half_t* __restrict__ Kq,
    const half_t* __restrict__ Vt,
    const float*  __restrict__ mask,   // [B*S] additive (nat-log domain)
    half_t* __restrict__ opart,
    float2* __restrict__ mlpart,
    int S, int H)
{
    __shared__ __align__(16) half_t Ks[64 * 64];        // [kv][d]   (swizzled)
    __shared__ __align__(16) half_t Vs[64 * 64];        // [d][kv]   (swizzled)
    __shared__ __align__(16) half_t Ps[4 * 32 * 64];    // per-wave P (swizzled)

    const float LOG2E = 1.44269504f;
    const float SCL2  = 0.125f * 1.44269504f;   // 1/sqrt(64) * log2(e)

    const int qt = blockIdx.x, h = blockIdx.y, z = blockIdx.z;
    const int b = z >> 1, hf = z & 1;
    const int tid = threadIdx.x, w = tid >> 6, lane = tid & 63;
    const int g = lane >> 4, ml = lane & 15, m7 = ml & 7;
    const int NHloc = gridDim.y;
    const int BNHS = 2 * NHloc * S;   // B*NH*S (B=2)

    const int q0 = qt * 128 + w * 32;
    const half_t* Qg = Q  + ((size_t)(b * S + q0)) * H + h * 64;
    const half_t* Kg = Kq + ((size_t)b * S) * H + h * 64;
    const half_t* Vg = Vt + ((size_t)b * H + h * 64) * (size_t)S;
    const float*  mk = mask + (size_t)b * S;

    half8 qf[2][2];
#pragma unroll
    for (int qi = 0; qi < 2; qi++)
#pragma unroll
        for (int kk = 0; kk < 2; kk++)
            qf[qi][kk] = *(const half8*)(Qg + (size_t)(qi * 16 + ml) * H + kk * 32 + g * 8);

    float m_[2] = {-1e30f, -1e30f}, l_[2] = {0.f, 0.f};
    f32x4 o[2][4];
#pragma unroll
    for (int qi = 0; qi < 2; qi++)
#pragma unroll
        for (int df = 0; df < 4; df++) o[qi][df] = zero4();

    half_t* Pw = &Ps[w * 32 * 64];
    const int srow = tid >> 3;            // staging row (round t adds 32)
    const int sc   = tid & 7;             // phys 16B chunk within row

    const int kvbeg = hf * (S >> 1), kvend = kvbeg + (S >> 1);
    for (int kv0 = kvbeg; kv0 < kvend; kv0 += 64) {
        __syncthreads();
#pragma unroll
        for (int t = 0; t < 2; t++) {
            int row = t * 32 + srow;
            int ck  = sc ^ (row & 7);     // source chunk for phys chunk sc
            gl_lds16(Kg + (size_t)(kv0 + row) * H + ck * 8, &Ks[(t * 256 + w * 64) * 8]);
            gl_lds16(Vg + (size_t)row * S + kv0 + ck * 8,   &Vs[(t * 256 + w * 64) * 8]);
        }
        __syncthreads();

        f32x4 s[2][4];
#pragma unroll
        for (int kvf = 0; kvf < 4; kvf++) {
            half8 k0 = lds_frag(&Ks[(kvf * 16 + ml) * 64 + ((0 + g) ^ m7) * 8]);
            half8 k1 = lds_frag(&Ks[(kvf * 16 + ml) * 64 + ((4 + g) ^ m7) * 8]);
            s[0][kvf] = __builtin_amdgcn_mfma_f32_16x16x32_f16(k0, qf[0][0], zero4(), 0, 0, 0);
            s[0][kvf] = __builtin_amdgcn_mfma_f32_16x16x32_f16(k1, qf[0][1], s[0][kvf], 0, 0, 0);
            s[1][kvf] = __builtin_amdgcn_mfma_f32_16x16x32_f16(k0, qf[1][0], zero4(), 0, 0, 0);
            s[1][kvf] = __builtin_amdgcn_mfma_f32_16x16x32_f16(k1, qf[1][1], s[1][kvf], 0, 0, 0);
        }
        // ---- scale + mask, log2 domain
#pragma unroll
        for (int kvf = 0; kvf < 4; kvf++) {
            float4 mv = *(const float4*)(mk + kv0 + kvf * 16 + g * 4);
#pragma unroll
            for (int qi = 0; qi < 2; qi++) {
                s[qi][kvf][0] = s[qi][kvf][0] * SCL2 + mv.x * LOG2E;
                s[qi][kvf][1] = s[qi][kvf][1] * SCL2 + mv.y * LOG2E;
                s[qi][kvf][2] = s[qi][kvf][2] * SCL2 + mv.z * LOG2E;
                s[qi][kvf][3] = s[qi][kvf][3] * SCL2 + mv.w * LOG2E;
            }
        }
        // ---- online softmax with defer-max (THR = 8 nats = 11.5 in log2)
        float alpha[2];
        bool  defer[2];
#pragma unroll
        for (int qi = 0; qi < 2; qi++) {
            float mx = -1e30f;
#pragma unroll
            for (int kvf = 0; kvf < 4; kvf++)
#pragma unroll
                for (int r = 0; r < 4; r++) mx = fmaxf(mx, s[qi][kvf][r]);
            mx = fmaxf(mx, __shfl_xor(mx, 16));
            mx = fmaxf(mx, __shfl_xor(mx, 32));
            defer[qi] = __all(mx <= m_[qi] + 11.5f);   // wave-uniform
            float mnew, al;
            if (defer[qi]) { mnew = m_[qi]; al = 1.f; }
            else           { mnew = fmaxf(m_[qi], mx); al = fexp2(m_[qi] - mnew); }
            alpha[qi] = al;
            m_[qi] = mnew;
            float ps = 0.f;
#pragma unroll
            for (int kvf = 0; kvf < 4; kvf++)
#pragma unroll
                for (int r = 0; r < 4; r++) {
                    float pv = fexp2(s[qi][kvf][r] - mnew);
                    s[qi][kvf][r] = pv; ps += pv;
                }
            ps += __shfl_xor(ps, 16);
            ps += __shfl_xor(ps, 32);
            l_[qi] = l_[qi] * al + ps;
#pragma unroll
            for (int kvf = 0; kvf < 4; kvf++) {
                half4v pk;
#pragma unroll
                for (int r = 0; r < 4; r++) pk[r] = (half_t)s[qi][kvf][r];
                *(half4v*)(Pw + (qi * 16 + ml) * 64 +
                           (((kvf * 2 + (g >> 1)) ^ m7) * 8) + (g & 1) * 4) = pk;
            }
        }
        // ---- O rescale, skipped when deferred (wave-uniform branches)
#pragma unroll
        for (int qi = 0; qi < 2; qi++) {
            if (!defer[qi]) {
#pragma unroll
                for (int r = 0; r < 4; r++) {
                    float a = __shfl(alpha[qi], (lane & 48) + g * 4 + r);
#pragma unroll
                    for (int df = 0; df < 4; df++) o[qi][df][r] *= a;
                }
            }
        }
#pragma unroll
        for (int kk = 0; kk < 2; kk++) {
            half8 pa0 = lds_frag(&Pw[(ml)      * 64 + ((kk * 4 + g) ^ m7) * 8]);
            half8 pa1 = lds_frag(&Pw[(16 + ml) * 64 + ((kk * 4 + g) ^ m7) * 8]);
#pragma unroll
            for (int df = 0; df < 4; df++) {
                half8 vb = lds_frag(&Vs[(df * 16 + ml) * 64 + ((kk * 4 + g) ^ m7) * 8]);
                o[0][df] = __builtin_amdgcn_mfma_f32_16x16x32_f16(pa0, vb, o[0][df], 0, 0, 0);
                o[1][df] = __builtin_amdgcn_mfma_f32_16x16x32_f16(pa1, vb, o[1][df], 0, 0, 0);
            }
        }
    }

    // write partials: unnormalized o (fp16) + per-row (m,l), m in log2 domain
    const size_t rowbase = (size_t)hf * BNHS + ((size_t)(b * NHloc + h)) * S + q0;
#pragma unroll
    for (int qi = 0; qi < 2; qi++) {
#pragma unroll
        for (int r = 0; r < 4; r++) {
            size_t ro = (rowbase + qi * 16 + g * 4 + r) * 64;
#pragma unroll
            for (int df = 0; df < 4; df++)
                opart[ro + df * 16 + ml] = (half_t)o[qi][df][r];
        }
    }
    if (g == 0) {
#pragma unroll
        for (int qi = 0; qi < 2; qi++)
            mlpart[rowbase + qi * 16 + ml] = make_float2(m_[qi], l_[qi]);
    }
}

// ---------------------------------------------------------------------------
// Merge the two kv-half partials -> ctx [B*S][H] fp16. m is log2-domain.
// rows = B*NH*S = 65536; hardcoded S=2048, H=1024, NH=16, B=2.
// ---------------------------------------------------------------------------
__global__ __launch_bounds__(256) void flash_merge(
    const half_t* __restrict__ opart,
    const float2* __restrict__ mlpart,
    half_t* __restrict__ ctx)
{
    int gid = blockIdx.x * 256 + threadIdx.x;   // 65536*16
    int row = gid >> 4, dg = (gid & 15) * 4;
    float2 a = mlpart[row], c = mlpart[65536 + row];
    float m  = fmaxf(a.x, c.x);
    float w1 = fexp2(a.x - m), w2 = fexp2(c.x - m);
    float inv = 1.f / (w1 * a.y + w2 * c.y);
    half4v o1 = *(const half4v*)&opart[(size_t)row * 64 + dg];
    half4v o2 = *(const half4v*)&opart[(size_t)(65536 + row) * 64 + dg];
    int b = row >> 15, hq = row & 32767;
    int h = hq >> 11, q = hq & 2047;
    half4v o;
#pragma unroll
    for (int i = 0; i < 4; i++)
        o[i] = (half_t)((w1 * (float)o1[i] + w2 * (float)o2[i]) * inv);
    *(half4v*)&ctx[((size_t)(b * 2048 + q)) * 1024 + h * 64 + dg] = o;
}

// ---------------------------------------------------------------------------
// W[K][N] fp32 -> Wt[N][K] fp16 (32x32 tiles), batched over grid.z
// ---------------------------------------------------------------------------
__global__ __launch_bounds__(256) void transpose_cast(
    const float* __restrict__ W, half_t* __restrict__ Wt, int Kd, int Nd)
{
    __shared__ float tile[32][33];
    size_t zoff = (size_t)blockIdx.z * Kd * Nd;
    const float* Wz = W + zoff;
    half_t* Wtz = Wt + zoff;
    int n0 = blockIdx.x * 32, k0 = blockIdx.y * 32;
    int tx = threadIdx.x & 31, ty = threadIdx.x >> 5;
#pragma unroll
    for (int j = 0; j < 4; j++)
        tile[ty + j * 8][tx] = Wz[(size_t)(k0 + ty + j * 8) * Nd + n0 + tx];
    __syncthreads();
#pragma unroll
    for (int j = 0; j < 4; j++)
        Wtz[(size_t)(n0 + ty + j * 8) * Kd + k0 + tx] = (half_t)tile[tx][ty + j * 8];
}

// Q/K/V weights -> per-layer fused [l][3][H][H] transposed fp16
__global__ __launch_bounds__(256) void transpose_qkv(
    const float* __restrict__ Wq, const float* __restrict__ Wk,
    const float* __restrict__ Wv, half_t* __restrict__ WT)
{
    __shared__ float tile[32][33];
    int z = blockIdx.z, l = z / 3, which = z % 3;
    const float* W = ((which == 0) ? Wq : (which == 1) ? Wk : Wv) + (size_t)l * 1024 * 1024;
    half_t* D = WT + ((size_t)l * 3 + which) * 1024 * 1024;
    int n0 = blockIdx.x * 32, k0 = blockIdx.y * 32;
    int tx = threadIdx.x & 31, ty = threadIdx.x >> 5;
#pragma unroll
    for (int j = 0; j < 4; j++)
        tile[ty + j * 8][tx] = W[(size_t)(k0 + ty + j * 8) * 1024 + n0 + tx];
    __syncthreads();
#pragma unroll
    for (int j = 0; j < 4; j++)
        D[(size_t)(n0 + ty + j * 8) * 1024 + k0 + tx] = (half_t)tile[tx][ty + j * 8];
}

__global__ __launch_bounds__(256) void cast_f32_f16(
    const float* __restrict__ in, half_t* __restrict__ out)
{
    int i = blockIdx.x * 256 + threadIdx.x;
    float4 v = ((const float4*)in)[i];
    half4v o; o[0] = (half_t)v.x; o[1] = (half_t)v.y; o[2] = (half_t)v.z; o[3] = (half_t)v.w;
    *(half4v*)(out + (size_t)i * 4) = o;
}

// ---------------------------------------------------------------------------
// LayerNorm over H=1024; emits fp32 (residual path) + fp16 (next GEMM input)
// ---------------------------------------------------------------------------
__global__ __launch_bounds__(256) void layernorm_k(
    const float* __restrict__ in,
    const float* __restrict__ gam, const float* __restrict__ bet,
    float* __restrict__ outf, half_t* __restrict__ outh)
{
    int row = blockIdx.x, tid = threadIdx.x;
    const float4 v = ((const float4*)(in + (size_t)row * 1024))[tid];
    float s = v.x + v.y + v.z + v.w;
    float q = v.x * v.x + v.y * v.y + v.z * v.z + v.w * v.w;
    for (int off = 32; off; off >>= 1) { s += __shfl_down(s, off); q += __shfl_down(q, off); }
    __shared__ float ss[4], sq[4];
    int w = tid >> 6;
    if ((tid & 63) == 0) { ss[w] = s; sq[w] = q; }
    __syncthreads();
    float S_ = ss[0] + ss[1] + ss[2] + ss[3];
    float Q_ = sq[0] + sq[1] + sq[2] + sq[3];
    float mean = S_ * (1.f / 1024.f);
    float var  = Q_ * (1.f / 1024.f) - mean * mean;
    float rstd = rsqrtf(var + 1e-5f);
    float4 gm = ((const float4*)gam)[tid];
    float4 bt = ((const float4*)bet)[tid];
    float y0 = (v.x - mean) * rstd * gm.x + bt.x;
    float y1 = (v.y - mean) * rstd * gm.y + bt.y;
    float y2 = (v.z - mean) * rstd * gm.z + bt.z;
    float y3 = (v.w - mean) * rstd * gm.w + bt.w;
    ((float4*)(outf + (size_t)row * 1024))[tid] = make_float4(y0, y1, y2, y3);
    half4v oh; oh[0] = (half_t)y0; oh[1] = (half_t)y1; oh[2] = (half_t)y2; oh[3] = (half_t)y3;
    *(half4v*)(outh + (size_t)row * 1024 + tid * 4) = oh;
}

// ---------------------------------------------------------------------------
extern "C" void kernel_launch(void* const* d_in, const int* in_sizes, int n_in,
                              void* d_out, int out_size, void* d_ws, size_t ws_size,
                              hipStream_t stream)
{
    const int Lc = 2, Bb = 2, S = 2048, Hh = 1024, NH = 16, FF = 4096;
    const int M = Bb * S;  // 4096

    const float* hs   = (const float*)d_in[0];
    const float* mask = (const float*)d_in[1];
    const float* Wq   = (const float*)d_in[2];  const float* bq  = (const float*)d_in[3];
    const float* Wk   = (const float*)d_in[4];  const float* bk  = (const float*)d_in[5];
    const float* Wv   = (const float*)d_in[6];  const float* bv  = (const float*)d_in[7];
    const float* Wao  = (const float*)d_in[8];  const float* bao = (const float*)d_in[9];
    const float* g1   = (const float*)d_in[10]; const float* b1  = (const float*)d_in[11];
    const float* Wi   = (const float*)d_in[12]; const float* bi  = (const float*)d_in[13];
    const float* Wo   = (const float*)d_in[14]; const float* bo  = (const float*)d_in[15];
    const float* g2   = (const float*)d_in[16]; const float* b2  = (const float*)d_in[17];

    char* p = (char*)d_ws;
    auto take = [&](size_t bytes) { char* r = p; p += (bytes + 255) & ~(size_t)255; return r; };

    half_t* WqkvT = (half_t*)take((size_t)Lc * 3 * Hh * Hh * 2);   // 12 MB
    half_t* WaoT  = (half_t*)take((size_t)Lc * Hh * Hh * 2);       //  4 MB
    half_t* WiT   = (half_t*)take((size_t)Lc * Hh * FF * 2);       // 16 MB
    half_t* WoT   = (half_t*)take((size_t)Lc * FF * Hh * 2);       // 16 MB
    half_t* xb    = (half_t*)take((size_t)M * Hh * 2);             //  8 MB
    half_t* Qb    = (half_t*)take((size_t)M * Hh * 2);             //  8 MB
    half_t* Kb2   = (half_t*)take((size_t)M * Hh * 2);             //  8 MB
    half_t* Vtb   = (half_t*)take((size_t)M * Hh * 2);             //  8 MB
    (void)          take((size_t)M * Hh * 2);                      //  8 MB pad (h1 span)
    half_t* h1    = Qb;   // FFN hidden [M][FF] fp16 reuses Qb..pad (32 MB)
    float*  t0    = (float*)take((size_t)M * Hh * 4);              // 16 MB
    float*  x1f   = (float*)take((size_t)M * Hh * 4);              // 16 MB
    half_t* x1b   = (half_t*)take((size_t)M * Hh * 2);             //  8 MB

    // flash partials alias dead-at-attention buffers:
    half_t* opart  = (half_t*)t0;    // 2*65536*64*2 B = 16.78 MB == sizeof(t0)
    float2* mlpart = (float2*)x1b;   // 2*65536*8 B = 1 MB

    dim3 tb(256);

    transpose_qkv<<<dim3(32, 32, Lc * 3), tb, 0, stream>>>(Wq, Wk, Wv, WqkvT);
    transpose_cast<<<dim3(32, 32, Lc), tb, 0, stream>>>(Wao, WaoT, Hh, Hh);
    transpose_cast<<<dim3(FF / 32, 32, Lc), tb, 0, stream>>>(Wi, WiT, Hh, FF);
    transpose_cast<<<dim3(32, FF / 32, Lc), tb, 0, stream>>>(Wo, WoT, FF, Hh);
    cast_f32_f16<<<dim3(M * Hh / 1024), tb, 0, stream>>>(hs, xb);

    const float* xres = hs;
    for (int l = 0; l < Lc; l++) {
        const half_t* WqkvTl = WqkvT + (size_t)l * 3 * Hh * Hh;
        const half_t* WaoTl  = WaoT  + (size_t)l * Hh * Hh;
        const half_t* WiTl   = WiT   + (size_t)l * Hh * FF;
        const half_t* WoTl   = WoT   + (size_t)l * FF * Hh;

        gemm256_qkv<<<dim3(3072 / 256, M / 256), dim3(512), 0, stream>>>(
            xb, WqkvTl, bq + l * Hh, bk + l * Hh, bv + l * Hh, Qb, Kb2, Vtb, M, Hh);

        flash_attn<<<dim3(S / 128, NH, Bb * 2), tb, 0, stream>>>(
            Qb, Kb2, Vtb, mask, opart, mlpart, S, Hh);
        flash_merge<<<dim3(Bb * NH * S * 16 / 256), tb, 0, stream>>>(opart, mlpart, xb);

        gemm_bt64<<<dim3(Hh / 64, M / 128), tb, 0, stream>>>(
            xb, WaoTl, bao + l * Hh, xres, t0, M, Hh, Hh);
        layernorm_k<<<dim3(M), tb, 0, stream>>>(t0, g1 + l * Hh, b1 + l * Hh, x1f, x1b);

        gemm256_bt<<<dim3(FF / 256, M / 256), dim3(512), 0, stream>>>(
            x1b, WiTl, bi + l * FF, nullptr, h1, M, FF, Hh, MODE_GELU);
        gemm_bt64<<<dim3(Hh / 64, M / 128), tb, 0, stream>>>(
            h1, WoTl, bo + l * Hh, x1f, t0, M, Hh, FF);

        float* outf = (l == Lc - 1) ? (float*)d_out : x1f;
        layernorm_k<<<dim3(M), tb, 0, stream>>>(t0, g2 + l * Hh, b2 + l * Hh, outf, xb);
        xres = x1f;
    }
}